// Round 5
// baseline (3732.172 us; speedup 1.0000x reference)
//
#include <hip/hip_runtime.h>

// ---------------------------------------------------------------------------
// Persistent 2-layer LSTM for MI355X (gfx950). Round-5:
//   - 512 blocks x 256 thr (2/CU). Weights in regs as bf16 B-fragments.
//   - h fragment-major in ws; K-loop = direct global->VGPR coherent u64 loads,
//     zero LDS staging, zero barriers inside the loop.
//   - NEW: sync via per-(layer,bc) fetch_add counters (16 total, 128B apart);
//     consumers poll with TWO lanes + s_sleep(2) backoff. Round-4's 64-lane
//     stamp-slot polling flooded the coherence fabric (~64x more poll lines)
//     and starved the data path (75ms outlier dispatches).
//   - Encoder xin staged before the poll (one merged barrier).
//   - Fence-free coherence: relaxed agent-scope atomics + s_waitcnt release.
// ---------------------------------------------------------------------------

typedef __attribute__((ext_vector_type(8))) short bf16x8;
typedef __attribute__((ext_vector_type(16))) float f32x16;

#define MFMA32(a, b, c) __builtin_amdgcn_mfma_f32_32x32x16_bf16((a), (b), (c), 0, 0, 0)
#define DEV static __device__ __forceinline__

constexpr int kSeq = 128;          // encoder steps
constexpr int kT = 175;            // total lstm steps
constexpr int kRB = 65536;         // bytes per (parity,layer,bc) h region

// workspace layout (bytes)
constexpr size_t kWsHbuf = 0;                               // [2][2][8] regions = 2 MB
constexpr size_t kWsYacc = 2ull * 2 * 8 * kRB;              // [2][512][8] f32 = 32 KB
constexpr size_t kWsCnt  = kWsYacc + 2ull * 512 * 8 * 4;    // [2][8] x 128B
constexpr size_t kWsRc   = kWsCnt + 2ull * 8 * 128;         // [2][8] x 64B
constexpr size_t kWsEnd  = kWsRc + 2ull * 8 * 64;
constexpr size_t kWsZeroBegin = kWsYacc;
constexpr size_t kWsZeroSize  = kWsEnd - kWsYacc;

DEV unsigned short f2bf(float f) {
  unsigned u = __float_as_uint(f);
  u += 0x7fffu + ((u >> 16) & 1u);
  return (unsigned short)(u >> 16);
}
DEV float bf2f(unsigned short s) { return __uint_as_float(((unsigned)s) << 16); }
DEV float sigf(float v) { return 1.0f / (1.0f + __expf(-v)); }
DEV float tanhf_(float v) { float e = __expf(2.0f * v); return 1.0f - 2.0f / (e + 1.0f); }
DEV f32x16 zero16() {
  f32x16 z;
#pragma unroll
  for (int i = 0; i < 16; ++i) z[i] = 0.0f;
  return z;
}
DEV bf16x8 pack8(const float* p) {
  float4 a = *(const float4*)p;
  float4 b = *(const float4*)(p + 4);
  bf16x8 r;
  r[0] = (short)f2bf(a.x); r[1] = (short)f2bf(a.y);
  r[2] = (short)f2bf(a.z); r[3] = (short)f2bf(a.w);
  r[4] = (short)f2bf(b.x); r[5] = (short)f2bf(b.y);
  r[6] = (short)f2bf(b.z); r[7] = (short)f2bf(b.w);
  return r;
}

// device-coherent (agent-scope) primitives ---------------------------------
DEV unsigned ald(const unsigned* p) {
  return __hip_atomic_load(p, __ATOMIC_RELAXED, __HIP_MEMORY_SCOPE_AGENT);
}
DEV unsigned long long ald64(const unsigned long long* p) {
  return __hip_atomic_load(p, __ATOMIC_RELAXED, __HIP_MEMORY_SCOPE_AGENT);
}
DEV void ast64(unsigned long long* p, unsigned long long v) {
  __hip_atomic_store(p, v, __ATOMIC_RELAXED, __HIP_MEMORY_SCOPE_AGENT);
}
DEV float aldf(const float* p) {
  return __hip_atomic_load(p, __ATOMIC_RELAXED, __HIP_MEMORY_SCOPE_AGENT);
}
DEV void astf(float* p, float v) {
  __hip_atomic_store(p, v, __ATOMIC_RELAXED, __HIP_MEMORY_SCOPE_AGENT);
}
DEV void aadd(unsigned* p) {  // no-return agent-scope increment
  __hip_atomic_fetch_add(p, 1u, __ATOMIC_RELAXED, __HIP_MEMORY_SCOPE_AGENT);
}
DEV void relwait() {  // drain own coherent stores to the coherence point
  __atomic_signal_fence(__ATOMIC_SEQ_CST);
  __builtin_amdgcn_s_waitcnt(0);
  __atomic_signal_fence(__ATOMIC_SEQ_CST);
}
// two-counter poll: lane0 polls (c0,t0), lane1 polls (c1,t1); others pass.
// Bounded (~1s cap). Call with one full wave.
DEV bool pollc(const unsigned* c0, unsigned t0, const unsigned* c1, unsigned t1) {
  const int ln = (int)(threadIdx.x & 63);
  const unsigned* p = (ln == 1) ? c1 : c0;
  const unsigned thr = (ln == 0) ? t0 : ((ln == 1) ? t1 : 0u);
  for (int it = 0; it < (1 << 22); ++it) {
    const unsigned v = (ln < 2) ? ald(p) : 0xffffffffu;
    if (__ballot(v < thr) == 0ull) {
      __atomic_signal_fence(__ATOMIC_ACQUIRE);
      return true;
    }
    __builtin_amdgcn_s_sleep(2);
  }
  return false;
}

// parts: [16 (kw,gate)][64 r][17 pad] bf16
#define PARTS_WRITE(accv, ms_, ns_)                                           \
  { const int gate_ = (ns_)*2 + gbit;                                         \
    _Pragma("unroll") for (int rg = 0; rg < 16; ++rg) {                       \
      const int r_ = (ms_)*32 + (rg & 3) + 4 * hi5 + 8 * (rg >> 2);           \
      partsB[((kw * 4 + gate_) * 64 + r_) * 17 + l15] = f2bf((accv)[rg]);     \
    } }

__global__ __launch_bounds__(256, 2) void lstm_persist(
    const float* __restrict__ x, const float* __restrict__ ft,
    const float* __restrict__ h0in, const float* __restrict__ c0in,
    const float* __restrict__ wih0, const float* __restrict__ whh0,
    const float* __restrict__ bih0, const float* __restrict__ bhh0,
    const float* __restrict__ wih1, const float* __restrict__ whh1,
    const float* __restrict__ bih1, const float* __restrict__ bhh1,
    const float* __restrict__ fcw, const float* __restrict__ fcb,
    float* __restrict__ out, char* __restrict__ ws) {
  __shared__ __attribute__((aligned(16))) unsigned short partsB[16 * 64 * 17];
  __shared__ __attribute__((aligned(16))) unsigned short xin[64 * 40];
  __shared__ __attribute__((aligned(16))) unsigned short hloc[64 * 24];
  __shared__ float biasl[4][16];
  __shared__ float fcwl[8][16];
  __shared__ unsigned bflag;

  const int bid = blockIdx.x;
  const int layer = bid >> 8;
  const int idx = bid & 255;
  const int bc = idx & 7;
  const int hc = idx >> 3;
  const int b0 = bc * 64;
  const int u0 = hc * 16;
  const int tid = threadIdx.x;
  const int kw = tid >> 6;
  const int lane = tid & 63;
  const int l31 = lane & 31, l15 = lane & 15, hi5 = lane >> 5, gbit = (lane >> 4) & 1;

  char* hbuf = ws + kWsHbuf;
  float* yacc = (float*)(ws + kWsYacc);
  unsigned* cntbase = (unsigned*)(ws + kWsCnt);
  unsigned* rc = (unsigned*)(ws + kWsRc);

  unsigned* cs0 = cntbase + (0 * 8 + bc) * 32;   // layer-0 counter for this bc
  unsigned* cs1 = cntbase + (1 * 8 + bc) * 32;   // layer-1 counter
  auto region = [&](int p, int l, int b) -> char* {
    return hbuf + (size_t)(((p * 2) + l) * 8 + b) * kRB;
  };

  bool alive = true;  // wave0: poll timeout kill-switch

  // ---- one-time: weights -> registers (bf16 B-fragments), index by m ----
  // wave kw handles ksteps jin = kw + 4m.  B-frag: n=lane&31, k=hi5*8+j.
  bf16x8 wf[2][16];
#pragma unroll
  for (int ns = 0; ns < 2; ++ns) {
    const int gate = ns * 2 + gbit;
    const int wrow = gate * 512 + u0 + l15;
    if (layer) {
#pragma unroll
      for (int m = 0; m < 16; ++m) {
        const int jg = kw + 4 * m;
        const int k0 = jg * 16 + hi5 * 8;
        const float* p = (k0 < 512) ? (wih1 + wrow * 512 + k0)
                                    : (whh1 + wrow * 512 + (k0 - 512));
        wf[ns][m] = pack8(p);
      }
    } else {
#pragma unroll
      for (int m = 0; m < 8; ++m) {
        const int jg = kw + 4 * m;
        wf[ns][m] = pack8(whh0 + wrow * 512 + jg * 16 + hi5 * 8);
      }
      if (kw < 2) wf[ns][8] = pack8(wih0 + wrow * 32 + kw * 16 + hi5 * 8);
    }
  }

  if (tid < 64) {
    const int g = tid >> 4, h = tid & 15;
    const int row = g * 512 + u0 + h;
    biasl[g][h] = layer ? (bih1[row] + bhh1[row]) : (bih0[row] + bhh0[row]);
  }
  if (layer && tid >= 64 && tid < 192) {
    const int t2 = tid - 64;
    fcwl[t2 >> 4][t2 & 15] = fcw[(t2 >> 4) * 512 + u0 + (t2 & 15)];
  }

  const int own_h = tid & 15;
  const int own_r0 = (tid >> 4) * 4;
  float cst[4];
  {
    const float cv = c0in[layer * 512 + u0 + own_h];
    cst[0] = cst[1] = cst[2] = cst[3] = cv;
  }

  // ---- prologue: write h(-1) into fragment-major region, add +1 ----
  {
    char* dst = region(layer ? 0 : 1, layer, bc);
    if (tid < 128) {
      const int r = tid >> 1, half = tid & 1;
      union { unsigned short s[8]; unsigned long long u[2]; } v;
#pragma unroll
      for (int k2 = 0; k2 < 8; ++k2)
        v.s[k2] = f2bf(h0in[layer * 512 + u0 + half * 8 + k2]);
      unsigned long long* dp =
          (unsigned long long*)(dst + ((u0 >> 3) + half) * 1024 + r * 16);
      ast64(dp, v.u[0]); ast64(dp + 1, v.u[1]);
    }
    relwait();
    __syncthreads();
    if (tid == 0) aadd(layer ? cs1 : cs0);
  }

  auto xin_store = [&](int r, int c4, float4 v) {
    const int gx = c4 >> 3, half = (c4 >> 2) & 1;
    uint2 pv;
    pv.x = (unsigned)f2bf(v.x) | ((unsigned)f2bf(v.y) << 16);
    pv.y = (unsigned)f2bf(v.z) | ((unsigned)f2bf(v.w) << 16);
    *(uint2*)&xin[r * 40 + ((gx ^ (r & 3)) << 3) + half * 4] = pv;
  };

  auto cell_update = [&]() {
#pragma unroll
    for (int i = 0; i < 4; ++i) {
      const int r = own_r0 + i;
      float ig = biasl[0][own_h], fg = biasl[1][own_h];
      float gg = biasl[2][own_h], og = biasl[3][own_h];
#pragma unroll
      for (int w2 = 0; w2 < 4; ++w2) {
        ig += bf2f(partsB[((w2 * 4 + 0) * 64 + r) * 17 + own_h]);
        fg += bf2f(partsB[((w2 * 4 + 1) * 64 + r) * 17 + own_h]);
        gg += bf2f(partsB[((w2 * 4 + 2) * 64 + r) * 17 + own_h]);
        og += bf2f(partsB[((w2 * 4 + 3) * 64 + r) * 17 + own_h]);
      }
      const float cv = sigf(fg) * cst[i] + sigf(ig) * tanhf_(gg);
      cst[i] = cv;
      hloc[r * 24 + own_h] = f2bf(sigf(og) * tanhf_(cv));
    }
  };

  auto h_publish = [&](char* dst) {  // 64 r x 16 units, coherent u64 stores
    if (tid < 128) {
      const int r = tid >> 1, half = tid & 1;
      union { uint4 q; unsigned long long u[2]; } v;
      v.q = *(const uint4*)&hloc[r * 24 + half * 8];
      unsigned long long* dp =
          (unsigned long long*)(dst + ((u0 >> 3) + half) * 1024 + r * 16);
      ast64(dp, v.u[0]); ast64(dp + 1, v.u[1]);
    }
  };

  if (layer == 0) {
    // =========================== LAYER 0 ===========================
    for (int t = 0; t < kT; ++t) {
      const unsigned c0thr = 32u * (unsigned)(t + 1);   // h0(t-1) published
      if (t < kSeq) {
        // stage xin (independent of h), then poll, one merged barrier
#pragma unroll
        for (int it = 0; it < 2; ++it) {
          const int u = tid + it * 256;
          const int r = u >> 3, c4 = (u & 7) * 4;
          xin_store(r, c4, *(const float4*)&x[(size_t)(t * 512 + b0 + r) * 32 + c4]);
        }
        if (kw == 0 && alive)
          alive = pollc(cs0, c0thr, cs1, 32u * (unsigned)t);  // WAR: L1(t-2) done
        __syncthreads();
      } else {
        if (kw == 0 && alive)
          alive = pollc(cs0, c0thr, cs1, 32u * (unsigned)(t + 1));  // y(t-1) ready
        __syncthreads();
        const int q = (t - 1) & 1;
        if (tid < 128) {
          const int r = tid >> 1, o4 = (tid & 1) * 4;
          const float* yp = &yacc[(size_t)(q * 512 + b0 + r) * 8 + o4];
          float4 v;
          v.x = aldf(yp + 0); v.y = aldf(yp + 1);
          v.z = aldf(yp + 2); v.w = aldf(yp + 3);
          const float4 bb = *(const float4*)&fcb[o4];
          v.x += bb.x; v.y += bb.y; v.z += bb.z; v.w += bb.w;
          if (hc == 0)
            *(float4*)&out[(size_t)((t - kSeq) * 512 + b0 + r) * 8 + o4] = v;
          xin_store(r, o4, v);
        }
        for (int u = tid; u < 384; u += 256) {
          const int r = u / 6, m = u - r * 6;
          xin_store(r, 8 + m * 4,
                    *(const float4*)&ft[(size_t)((t - kSeq) * 512 + b0 + r) * 24 + m * 4]);
        }
        __syncthreads();  // xin ready, yacc reads done
        if (tid == 0) {
          const unsigned old = __hip_atomic_fetch_add(rc + (q * 8 + bc) * 16, 1u,
                                                      __ATOMIC_RELAXED,
                                                      __HIP_MEMORY_SCOPE_AGENT);
          bflag = (old == 31u) ? 1u : 0u;
        }
        __syncthreads();
        if (bflag) {  // last reader zeroes yacc[q] slice for reuse
          for (int u = tid; u < 512; u += 256)
            astf(&yacc[(size_t)q * 512 * 8 + (size_t)b0 * 8 + u], 0.0f);
          relwait();
          __syncthreads();
          if (tid == 0)
            __hip_atomic_store(rc + (q * 8 + bc) * 16, 0u, __ATOMIC_RELAXED,
                               __HIP_MEMORY_SCOPE_AGENT);
        }
      }

      // K-loop: 8 ksteps (jin = kw+4m, m=0..7), direct coherent A loads
      f32x16 acc00 = zero16(), acc01 = zero16(), acc10 = zero16(), acc11 = zero16();
      const char* hb0 = region((t - 1) & 1, 0, bc);
      unsigned long long abuf[2][16];
#pragma unroll
      for (int i = 0; i < 4; ++i) {  // prefetch group 0
        const size_t off = (size_t)((2 * (kw + 4 * i) + hi5) * 64 + l31) * 16;
        const unsigned long long* p = (const unsigned long long*)(hb0 + off);
        abuf[0][i * 4 + 0] = ald64(p);
        abuf[0][i * 4 + 1] = ald64(p + 1);
        const unsigned long long* q2 = (const unsigned long long*)(hb0 + off + 512);
        abuf[0][i * 4 + 2] = ald64(q2);
        abuf[0][i * 4 + 3] = ald64(q2 + 1);
      }
#pragma unroll
      for (int g = 0; g < 2; ++g) {
        if (g == 0) {
#pragma unroll
          for (int i = 0; i < 4; ++i) {
            const int m = 4 + i;
            const size_t off = (size_t)((2 * (kw + 4 * m) + hi5) * 64 + l31) * 16;
            const unsigned long long* p = (const unsigned long long*)(hb0 + off);
            abuf[1][i * 4 + 0] = ald64(p);
            abuf[1][i * 4 + 1] = ald64(p + 1);
            const unsigned long long* q2 = (const unsigned long long*)(hb0 + off + 512);
            abuf[1][i * 4 + 2] = ald64(q2);
            abuf[1][i * 4 + 3] = ald64(q2 + 1);
          }
        }
#pragma unroll
        for (int i = 0; i < 4; ++i) {
          const int m = g * 4 + i;
          union { unsigned long long u[2]; bf16x8 v; } a0, a1;
          a0.u[0] = abuf[g][i * 4 + 0]; a0.u[1] = abuf[g][i * 4 + 1];
          a1.u[0] = abuf[g][i * 4 + 2]; a1.u[1] = abuf[g][i * 4 + 3];
          acc00 = MFMA32(a0.v, wf[0][m], acc00);
          acc01 = MFMA32(a0.v, wf[1][m], acc01);
          acc10 = MFMA32(a1.v, wf[0][m], acc10);
          acc11 = MFMA32(a1.v, wf[1][m], acc11);
        }
      }
      if (kw < 2) {  // x-part (ksteps 32/33) from LDS xin
#pragma unroll
        for (int ms = 0; ms < 2; ++ms) {
          const int r = ms * 32 + l31;
          const int gx = kw * 2 + hi5;
          const bf16x8 a = *(const bf16x8*)&xin[r * 40 + ((gx ^ (r & 3)) << 3)];
          if (ms == 0) {
            acc00 = MFMA32(a, wf[0][8], acc00);
            acc01 = MFMA32(a, wf[1][8], acc01);
          } else {
            acc10 = MFMA32(a, wf[0][8], acc10);
            acc11 = MFMA32(a, wf[1][8], acc11);
          }
        }
      }
      PARTS_WRITE(acc00, 0, 0); PARTS_WRITE(acc01, 0, 1);
      PARTS_WRITE(acc10, 1, 0); PARTS_WRITE(acc11, 1, 1);
      __syncthreads();
      cell_update();
      __syncthreads();
      h_publish(region(t & 1, 0, bc));
      relwait();
      __syncthreads();
      if (tid == 0) aadd(cs0);
    }
    // final prediction y(174) -> out[47]
    if (hc == 0) {
      if (kw == 0 && alive)
        alive = pollc(cs1, 32u * (unsigned)(kT + 1), cs1, 0u);
      __syncthreads();
      for (int u = tid; u < 512; u += 256) {
        const int r = u >> 3, o = u & 7;
        out[(size_t)(47 * 512 + b0 + r) * 8 + o] =
            aldf(&yacc[(size_t)(b0 + r) * 8 + o]) + fcb[o];
      }
    }
  } else {
    // =========================== LAYER 1 ===========================
    for (int t = 0; t < kT; ++t) {
      if (kw == 0 && alive)  // h0(t) done; h1(t-1) done (data + WAR)
        alive = pollc(cs0, 32u * (unsigned)(t + 2), cs1, 32u * (unsigned)(t + 1));
      __syncthreads();

      f32x16 acc00 = zero16(), acc01 = zero16(), acc10 = zero16(), acc11 = zero16();
      const char* hbA = region(t & 1, 0, bc);   // h0(t), ksteps 0..31
      const char* hbB = region(t & 1, 1, bc);   // h1(t-1), ksteps 32..63
      unsigned long long abuf[2][16];
#pragma unroll
      for (int i = 0; i < 4; ++i) {  // prefetch group 0
        const char* base = hbA;
        const size_t off = (size_t)((2 * (kw + 4 * i) + hi5) * 64 + l31) * 16;
        const unsigned long long* p = (const unsigned long long*)(base + off);
        abuf[0][i * 4 + 0] = ald64(p);
        abuf[0][i * 4 + 1] = ald64(p + 1);
        const unsigned long long* q2 = (const unsigned long long*)(base + off + 512);
        abuf[0][i * 4 + 2] = ald64(q2);
        abuf[0][i * 4 + 3] = ald64(q2 + 1);
      }
#pragma unroll
      for (int g = 0; g < 4; ++g) {
        if (g < 3) {
          const int gn = g + 1;
#pragma unroll
          for (int i = 0; i < 4; ++i) {
            const int m = gn * 4 + i;
            const char* base = (m < 8) ? hbA : hbB;
            const int jl = (kw + 4 * m) & 31;
            const size_t off = (size_t)((2 * jl + hi5) * 64 + l31) * 16;
            const unsigned long long* p = (const unsigned long long*)(base + off);
            abuf[gn & 1][i * 4 + 0] = ald64(p);
            abuf[gn & 1][i * 4 + 1] = ald64(p + 1);
            const unsigned long long* q2 = (const unsigned long long*)(base + off + 512);
            abuf[gn & 1][i * 4 + 2] = ald64(q2);
            abuf[gn & 1][i * 4 + 3] = ald64(q2 + 1);
          }
        }
#pragma unroll
        for (int i = 0; i < 4; ++i) {
          const int m = g * 4 + i;
          union { unsigned long long u[2]; bf16x8 v; } a0, a1;
          a0.u[0] = abuf[g & 1][i * 4 + 0]; a0.u[1] = abuf[g & 1][i * 4 + 1];
          a1.u[0] = abuf[g & 1][i * 4 + 2]; a1.u[1] = abuf[g & 1][i * 4 + 3];
          acc00 = MFMA32(a0.v, wf[0][m], acc00);
          acc01 = MFMA32(a0.v, wf[1][m], acc01);
          acc10 = MFMA32(a1.v, wf[0][m], acc10);
          acc11 = MFMA32(a1.v, wf[1][m], acc11);
        }
      }
      PARTS_WRITE(acc00, 0, 0); PARTS_WRITE(acc01, 0, 1);
      PARTS_WRITE(acc10, 1, 0); PARTS_WRITE(acc11, 1, 1);
      __syncthreads();
      cell_update();
      __syncthreads();
      h_publish(region((t & 1) ^ 1, 1, bc));
      if (t >= kSeq - 1) {  // y(t) partials -> yacc[t&1]
        const int q = t & 1;
#pragma unroll
        for (int rep = 0; rep < 2; ++rep) {
          const int i2 = tid + rep * 256;
          const int r = i2 >> 3, o = i2 & 7;
          float s = 0.0f;
#pragma unroll
          for (int h2 = 0; h2 < 16; ++h2)
            s += bf2f(hloc[r * 24 + h2]) * fcwl[o][h2];
          atomicAdd(&yacc[(size_t)(q * 512 + b0 + r) * 8 + o], s);
        }
      }
      relwait();
      __syncthreads();
      if (tid == 0) aadd(cs1);
    }
  }
}

extern "C" void kernel_launch(void* const* d_in, const int* in_sizes, int n_in,
                              void* d_out, int out_size, void* d_ws, size_t ws_size,
                              hipStream_t stream) {
  (void)in_sizes; (void)n_in; (void)out_size; (void)ws_size;
  hipMemsetAsync((char*)d_ws + kWsZeroBegin, 0, kWsZeroSize, stream);

  const float* x    = (const float*)d_in[0];
  const float* ft   = (const float*)d_in[1];
  const float* h0in = (const float*)d_in[2];
  const float* c0in = (const float*)d_in[3];
  const float* wih0 = (const float*)d_in[4];
  const float* whh0 = (const float*)d_in[5];
  const float* bih0 = (const float*)d_in[6];
  const float* bhh0 = (const float*)d_in[7];
  const float* wih1 = (const float*)d_in[8];
  const float* whh1 = (const float*)d_in[9];
  const float* bih1 = (const float*)d_in[10];
  const float* bhh1 = (const float*)d_in[11];
  const float* fcw  = (const float*)d_in[12];
  const float* fcb  = (const float*)d_in[13];
  float* out = (float*)d_out;
  char* ws = (char*)d_ws;

  void* args[] = {&x, &ft, &h0in, &c0in, &wih0, &whh0, &bih0, &bhh0,
                  &wih1, &whh1, &bih1, &bhh1, &fcw, &fcb, &out, &ws};
  hipError_t err = hipLaunchCooperativeKernel((void*)lstm_persist, dim3(512),
                                              dim3(256), args, 0, stream);
  if (err != hipSuccess) {
    lstm_persist<<<dim3(512), dim3(256), 0, stream>>>(
        x, ft, h0in, c0in, wih0, whh0, bih0, bhh0,
        wih1, whh1, bih1, bhh1, fcw, fcb, out, ws);
  }
}

// Round 6
// 3477.049 us; speedup vs baseline: 1.0734x; 1.0734x over previous
//
#include <hip/hip_runtime.h>

// ---------------------------------------------------------------------------
// Persistent 2-layer LSTM for MI355X (gfx950). Round-6:
//   - 512 blocks x 256 thr (2/CU). Weights in regs as bf16 B-fragments.
//   - h fragment-major in ws; K-loop = direct global->VGPR coherent u64 loads,
//     zero LDS staging, zero barriers inside the loop.
//   - NEW signaling: producers fetch_add a cnt line NOBODY polls; the last
//     producer (old&31==31) writes step# to 4 replicated broadcast lines;
//     consumers poll ONE lane on ONE replica. Rounds 4/5 saturated a single
//     MALL line (~500 ops/us vs ~100 sustainable) -> ~15us/step queueing.
//   - NEW: parts exchange in fp32 (LDS [16][64][17] f32): no f2bf/cvt VALU.
//   - Fence-free coherence: relaxed agent-scope atomics + s_waitcnt release.
// ---------------------------------------------------------------------------

typedef __attribute__((ext_vector_type(8))) short bf16x8;
typedef __attribute__((ext_vector_type(16))) float f32x16;

#define MFMA32(a, b, c) __builtin_amdgcn_mfma_f32_32x32x16_bf16((a), (b), (c), 0, 0, 0)
#define DEV static __device__ __forceinline__

constexpr int kSeq = 128;          // encoder steps
constexpr int kT = 175;            // total lstm steps
constexpr int kRB = 65536;         // bytes per (parity,layer,bc) h region

// workspace layout (bytes)
constexpr size_t kWsHbuf = 0;                               // [2][2][8] regions = 2 MB
constexpr size_t kWsYacc = 2ull * 2 * 8 * kRB;              // [2][512][8] f32 = 32 KB
constexpr size_t kWsCnt  = kWsYacc + 2ull * 512 * 8 * 4;    // [2][8] x 128B (RMW only)
constexpr size_t kWsBc   = kWsCnt + 2ull * 8 * 128;         // [2][8][4] x 64B (poll only)
constexpr size_t kWsRc   = kWsBc + 2ull * 8 * 4 * 64;       // [2][8] x 64B
constexpr size_t kWsEnd  = kWsRc + 2ull * 8 * 64;
constexpr size_t kWsZeroBegin = kWsYacc;
constexpr size_t kWsZeroSize  = kWsEnd - kWsYacc;

DEV unsigned short f2bf(float f) {
  unsigned u = __float_as_uint(f);
  u += 0x7fffu + ((u >> 16) & 1u);
  return (unsigned short)(u >> 16);
}
DEV float bf2f(unsigned short s) { return __uint_as_float(((unsigned)s) << 16); }
DEV float sigf(float v) { return 1.0f / (1.0f + __expf(-v)); }
DEV float tanhf_(float v) { float e = __expf(2.0f * v); return 1.0f - 2.0f / (e + 1.0f); }
DEV f32x16 zero16() {
  f32x16 z;
#pragma unroll
  for (int i = 0; i < 16; ++i) z[i] = 0.0f;
  return z;
}
DEV bf16x8 pack8(const float* p) {
  float4 a = *(const float4*)p;
  float4 b = *(const float4*)(p + 4);
  bf16x8 r;
  r[0] = (short)f2bf(a.x); r[1] = (short)f2bf(a.y);
  r[2] = (short)f2bf(a.z); r[3] = (short)f2bf(a.w);
  r[4] = (short)f2bf(b.x); r[5] = (short)f2bf(b.y);
  r[6] = (short)f2bf(b.z); r[7] = (short)f2bf(b.w);
  return r;
}

// device-coherent (agent-scope) primitives ---------------------------------
DEV unsigned ald(const unsigned* p) {
  return __hip_atomic_load(p, __ATOMIC_RELAXED, __HIP_MEMORY_SCOPE_AGENT);
}
DEV void ast(unsigned* p, unsigned v) {
  __hip_atomic_store(p, v, __ATOMIC_RELAXED, __HIP_MEMORY_SCOPE_AGENT);
}
DEV unsigned long long ald64(const unsigned long long* p) {
  return __hip_atomic_load(p, __ATOMIC_RELAXED, __HIP_MEMORY_SCOPE_AGENT);
}
DEV void ast64(unsigned long long* p, unsigned long long v) {
  __hip_atomic_store(p, v, __ATOMIC_RELAXED, __HIP_MEMORY_SCOPE_AGENT);
}
DEV float aldf(const float* p) {
  return __hip_atomic_load(p, __ATOMIC_RELAXED, __HIP_MEMORY_SCOPE_AGENT);
}
DEV void astf(float* p, float v) {
  __hip_atomic_store(p, v, __ATOMIC_RELAXED, __HIP_MEMORY_SCOPE_AGENT);
}
DEV unsigned afadd(unsigned* p) {  // returning agent-scope increment
  return __hip_atomic_fetch_add(p, 1u, __ATOMIC_RELAXED, __HIP_MEMORY_SCOPE_AGENT);
}
DEV void relwait() {  // drain own coherent stores to the coherence point
  __atomic_signal_fence(__ATOMIC_SEQ_CST);
  __builtin_amdgcn_s_waitcnt(0);
  __atomic_signal_fence(__ATOMIC_SEQ_CST);
}
// two-line poll: lane0 polls (p0,t0), lane1 polls (p1,t1); others pass.
DEV bool pollb(const unsigned* p0, unsigned t0, const unsigned* p1, unsigned t1) {
  const int ln = (int)(threadIdx.x & 63);
  const unsigned* p = (ln == 1) ? p1 : p0;
  const unsigned thr = (ln == 0) ? t0 : ((ln == 1) ? t1 : 0u);
  for (int it = 0; it < (1 << 22); ++it) {
    const unsigned v = (ln < 2) ? ald(p) : 0xffffffffu;
    if (__ballot((ln < 2) && (v < thr)) == 0ull) {
      __atomic_signal_fence(__ATOMIC_ACQUIRE);
      return true;
    }
    __builtin_amdgcn_s_sleep(2);
  }
  return false;
}

// parts: [16 (kw,gate)][64 r][17 pad] fp32
#define PARTS_WRITE(accv, ms_, ns_)                                           \
  { const int gate_ = (ns_)*2 + gbit;                                         \
    _Pragma("unroll") for (int rg = 0; rg < 16; ++rg) {                       \
      const int r_ = (ms_)*32 + (rg & 3) + 4 * hi5 + 8 * (rg >> 2);           \
      partsF[((kw * 4 + gate_) * 64 + r_) * 17 + l15] = (accv)[rg];           \
    } }

__global__ __launch_bounds__(256, 2) void lstm_persist(
    const float* __restrict__ x, const float* __restrict__ ft,
    const float* __restrict__ h0in, const float* __restrict__ c0in,
    const float* __restrict__ wih0, const float* __restrict__ whh0,
    const float* __restrict__ bih0, const float* __restrict__ bhh0,
    const float* __restrict__ wih1, const float* __restrict__ whh1,
    const float* __restrict__ bih1, const float* __restrict__ bhh1,
    const float* __restrict__ fcw, const float* __restrict__ fcb,
    float* __restrict__ out, char* __restrict__ ws) {
  __shared__ __attribute__((aligned(16))) float partsF[16 * 64 * 17];  // 69.6 KB
  __shared__ __attribute__((aligned(16))) unsigned short xin[64 * 40];
  __shared__ __attribute__((aligned(16))) unsigned short hloc[64 * 24];
  __shared__ float biasl[4][16];
  __shared__ float fcwl[8][16];
  __shared__ unsigned bflag;

  const int bid = blockIdx.x;
  const int layer = bid >> 8;
  const int idx = bid & 255;
  const int bc = idx & 7;
  const int hc = idx >> 3;
  const int b0 = bc * 64;
  const int u0 = hc * 16;
  const int tid = threadIdx.x;
  const int kw = tid >> 6;
  const int lane = tid & 63;
  const int l31 = lane & 31, l15 = lane & 15, hi5 = lane >> 5, gbit = (lane >> 4) & 1;

  char* hbuf = ws + kWsHbuf;
  float* yacc = (float*)(ws + kWsYacc);
  unsigned* cntb = (unsigned*)(ws + kWsCnt);
  unsigned* bcb = (unsigned*)(ws + kWsBc);
  unsigned* rc = (unsigned*)(ws + kWsRc);

  unsigned* cnt0 = cntb + (0 * 8 + bc) * 32;           // RMW-only lines
  unsigned* cnt1 = cntb + (1 * 8 + bc) * 32;
  const int rep = hc & 3;                              // replica pick
  unsigned* b0l = bcb + ((0 * 8 + bc) * 4 + rep) * 16; // poll-only lines
  unsigned* b1l = bcb + ((1 * 8 + bc) * 4 + rep) * 16;
  auto region = [&](int p, int l, int b) -> char* {
    return hbuf + (size_t)(((p * 2) + l) * 8 + b) * kRB;
  };
  // producer end-of-phase signal: fetch_add; last writes broadcast replicas
  auto signal = [&](unsigned* cl, int lyr) {
    const unsigned old = afadd(cl);
    if ((old & 31u) == 31u) {
      const unsigned v = (old + 1u) >> 5;
      unsigned* base = bcb + (lyr * 8 + bc) * 4 * 16;
#pragma unroll
      for (int r2 = 0; r2 < 4; ++r2) ast(base + r2 * 16, v);
    }
  };

  bool alive = true;  // wave0: poll timeout kill-switch

  // ---- one-time: weights -> registers (bf16 B-fragments), index by m ----
  bf16x8 wf[2][16];
#pragma unroll
  for (int ns = 0; ns < 2; ++ns) {
    const int gate = ns * 2 + gbit;
    const int wrow = gate * 512 + u0 + l15;
    if (layer) {
#pragma unroll
      for (int m = 0; m < 16; ++m) {
        const int jg = kw + 4 * m;
        const int k0 = jg * 16 + hi5 * 8;
        const float* p = (k0 < 512) ? (wih1 + wrow * 512 + k0)
                                    : (whh1 + wrow * 512 + (k0 - 512));
        wf[ns][m] = pack8(p);
      }
    } else {
#pragma unroll
      for (int m = 0; m < 8; ++m) {
        const int jg = kw + 4 * m;
        wf[ns][m] = pack8(whh0 + wrow * 512 + jg * 16 + hi5 * 8);
      }
      if (kw < 2) wf[ns][8] = pack8(wih0 + wrow * 32 + kw * 16 + hi5 * 8);
    }
  }

  if (tid < 64) {
    const int g = tid >> 4, h = tid & 15;
    const int row = g * 512 + u0 + h;
    biasl[g][h] = layer ? (bih1[row] + bhh1[row]) : (bih0[row] + bhh0[row]);
  }
  if (layer && tid >= 64 && tid < 192) {
    const int t2 = tid - 64;
    fcwl[t2 >> 4][t2 & 15] = fcw[(t2 >> 4) * 512 + u0 + (t2 & 15)];
  }

  const int own_h = tid & 15;
  const int own_r0 = (tid >> 4) * 4;
  float cst[4];
  {
    const float cv = c0in[layer * 512 + u0 + own_h];
    cst[0] = cst[1] = cst[2] = cst[3] = cv;
  }

  // ---- prologue: write h(-1) into fragment-major region, signal ----
  {
    char* dst = region(layer ? 0 : 1, layer, bc);
    if (tid < 128) {
      const int r = tid >> 1, half = tid & 1;
      union { unsigned short s[8]; unsigned long long u[2]; } v;
#pragma unroll
      for (int k2 = 0; k2 < 8; ++k2)
        v.s[k2] = f2bf(h0in[layer * 512 + u0 + half * 8 + k2]);
      unsigned long long* dp =
          (unsigned long long*)(dst + ((u0 >> 3) + half) * 1024 + r * 16);
      ast64(dp, v.u[0]); ast64(dp + 1, v.u[1]);
    }
    relwait();
    __syncthreads();
    if (tid == 0) signal(layer ? cnt1 : cnt0, layer);
  }

  auto xin_store = [&](int r, int c4, float4 v) {
    const int gx = c4 >> 3, half = (c4 >> 2) & 1;
    uint2 pv;
    pv.x = (unsigned)f2bf(v.x) | ((unsigned)f2bf(v.y) << 16);
    pv.y = (unsigned)f2bf(v.z) | ((unsigned)f2bf(v.w) << 16);
    *(uint2*)&xin[r * 40 + ((gx ^ (r & 3)) << 3) + half * 4] = pv;
  };

  auto cell_update = [&]() {
#pragma unroll
    for (int i = 0; i < 4; ++i) {
      const int r = own_r0 + i;
      float ig = biasl[0][own_h], fg = biasl[1][own_h];
      float gg = biasl[2][own_h], og = biasl[3][own_h];
#pragma unroll
      for (int w2 = 0; w2 < 4; ++w2) {
        ig += partsF[((w2 * 4 + 0) * 64 + r) * 17 + own_h];
        fg += partsF[((w2 * 4 + 1) * 64 + r) * 17 + own_h];
        gg += partsF[((w2 * 4 + 2) * 64 + r) * 17 + own_h];
        og += partsF[((w2 * 4 + 3) * 64 + r) * 17 + own_h];
      }
      const float cv = sigf(fg) * cst[i] + sigf(ig) * tanhf_(gg);
      cst[i] = cv;
      hloc[r * 24 + own_h] = f2bf(sigf(og) * tanhf_(cv));
    }
  };

  auto h_publish = [&](char* dst) {  // 64 r x 16 units, coherent u64 stores
    if (tid < 128) {
      const int r = tid >> 1, half = tid & 1;
      union { uint4 q; unsigned long long u[2]; } v;
      v.q = *(const uint4*)&hloc[r * 24 + half * 8];
      unsigned long long* dp =
          (unsigned long long*)(dst + ((u0 >> 3) + half) * 1024 + r * 16);
      ast64(dp, v.u[0]); ast64(dp + 1, v.u[1]);
    }
  };

  if (layer == 0) {
    // =========================== LAYER 0 ===========================
    for (int t = 0; t < kT; ++t) {
      if (t < kSeq) {
        // stage xin (independent of h), then poll, one merged barrier
#pragma unroll
        for (int it = 0; it < 2; ++it) {
          const int u = tid + it * 256;
          const int r = u >> 3, c4 = (u & 7) * 4;
          xin_store(r, c4, *(const float4*)&x[(size_t)(t * 512 + b0 + r) * 32 + c4]);
        }
        if (kw == 0 && alive)  // h0(t-1) ready; WAR: L1 done with h0(t-2)
          alive = pollb(b0l, (unsigned)(t + 1), b1l, (unsigned)t);
        __syncthreads();
      } else {
        if (kw == 0 && alive)  // h0(t-1); y(t-1) ready (L1 step t-1 done)
          alive = pollb(b0l, (unsigned)(t + 1), b1l, (unsigned)(t + 1));
        __syncthreads();
        const int q = (t - 1) & 1;
        if (tid < 128) {
          const int r = tid >> 1, o4 = (tid & 1) * 4;
          const float* yp = &yacc[(size_t)(q * 512 + b0 + r) * 8 + o4];
          float4 v;
          v.x = aldf(yp + 0); v.y = aldf(yp + 1);
          v.z = aldf(yp + 2); v.w = aldf(yp + 3);
          const float4 bb = *(const float4*)&fcb[o4];
          v.x += bb.x; v.y += bb.y; v.z += bb.z; v.w += bb.w;
          if (hc == 0)
            *(float4*)&out[(size_t)((t - kSeq) * 512 + b0 + r) * 8 + o4] = v;
          xin_store(r, o4, v);
        }
        for (int u = tid; u < 384; u += 256) {
          const int r = u / 6, m = u - r * 6;
          xin_store(r, 8 + m * 4,
                    *(const float4*)&ft[(size_t)((t - kSeq) * 512 + b0 + r) * 24 + m * 4]);
        }
        __syncthreads();  // xin ready, yacc reads done
        if (tid == 0) {
          const unsigned old = afadd(rc + (q * 8 + bc) * 16);
          bflag = (old == 31u) ? 1u : 0u;
        }
        __syncthreads();
        if (bflag) {  // last reader zeroes yacc[q] slice for reuse
          for (int u = tid; u < 512; u += 256)
            astf(&yacc[(size_t)q * 512 * 8 + (size_t)b0 * 8 + u], 0.0f);
          relwait();
          __syncthreads();
          if (tid == 0)
            __hip_atomic_store(rc + (q * 8 + bc) * 16, 0u, __ATOMIC_RELAXED,
                               __HIP_MEMORY_SCOPE_AGENT);
        }
      }

      // K-loop: 8 ksteps (jin = kw+4m, m=0..7), direct coherent A loads
      f32x16 acc00 = zero16(), acc01 = zero16(), acc10 = zero16(), acc11 = zero16();
      const char* hb0 = region((t - 1) & 1, 0, bc);
      unsigned long long abuf[2][16];
#pragma unroll
      for (int i = 0; i < 4; ++i) {  // prefetch group 0
        const size_t off = (size_t)((2 * (kw + 4 * i) + hi5) * 64 + l31) * 16;
        const unsigned long long* p = (const unsigned long long*)(hb0 + off);
        abuf[0][i * 4 + 0] = ald64(p);
        abuf[0][i * 4 + 1] = ald64(p + 1);
        const unsigned long long* q2 = (const unsigned long long*)(hb0 + off + 512);
        abuf[0][i * 4 + 2] = ald64(q2);
        abuf[0][i * 4 + 3] = ald64(q2 + 1);
      }
#pragma unroll
      for (int g = 0; g < 2; ++g) {
        if (g == 0) {
#pragma unroll
          for (int i = 0; i < 4; ++i) {
            const int m = 4 + i;
            const size_t off = (size_t)((2 * (kw + 4 * m) + hi5) * 64 + l31) * 16;
            const unsigned long long* p = (const unsigned long long*)(hb0 + off);
            abuf[1][i * 4 + 0] = ald64(p);
            abuf[1][i * 4 + 1] = ald64(p + 1);
            const unsigned long long* q2 = (const unsigned long long*)(hb0 + off + 512);
            abuf[1][i * 4 + 2] = ald64(q2);
            abuf[1][i * 4 + 3] = ald64(q2 + 1);
          }
        }
#pragma unroll
        for (int i = 0; i < 4; ++i) {
          const int m = g * 4 + i;
          union { unsigned long long u[2]; bf16x8 v; } a0, a1;
          a0.u[0] = abuf[g][i * 4 + 0]; a0.u[1] = abuf[g][i * 4 + 1];
          a1.u[0] = abuf[g][i * 4 + 2]; a1.u[1] = abuf[g][i * 4 + 3];
          acc00 = MFMA32(a0.v, wf[0][m], acc00);
          acc01 = MFMA32(a0.v, wf[1][m], acc01);
          acc10 = MFMA32(a1.v, wf[0][m], acc10);
          acc11 = MFMA32(a1.v, wf[1][m], acc11);
        }
      }
      if (kw < 2) {  // x-part (ksteps 32/33) from LDS xin
#pragma unroll
        for (int ms = 0; ms < 2; ++ms) {
          const int r = ms * 32 + l31;
          const int gx = kw * 2 + hi5;
          const bf16x8 a = *(const bf16x8*)&xin[r * 40 + ((gx ^ (r & 3)) << 3)];
          if (ms == 0) {
            acc00 = MFMA32(a, wf[0][8], acc00);
            acc01 = MFMA32(a, wf[1][8], acc01);
          } else {
            acc10 = MFMA32(a, wf[0][8], acc10);
            acc11 = MFMA32(a, wf[1][8], acc11);
          }
        }
      }
      PARTS_WRITE(acc00, 0, 0); PARTS_WRITE(acc01, 0, 1);
      PARTS_WRITE(acc10, 1, 0); PARTS_WRITE(acc11, 1, 1);
      __syncthreads();
      cell_update();
      __syncthreads();
      h_publish(region(t & 1, 0, bc));
      relwait();
      __syncthreads();
      if (tid == 0) signal(cnt0, 0);
    }
    // final prediction y(174) -> out[47]
    if (hc == 0) {
      if (kw == 0 && alive)
        alive = pollb(b1l, (unsigned)(kT + 1), b1l, (unsigned)(kT + 1));
      __syncthreads();
      for (int u = tid; u < 512; u += 256) {
        const int r = u >> 3, o = u & 7;
        out[(size_t)(47 * 512 + b0 + r) * 8 + o] =
            aldf(&yacc[(size_t)(b0 + r) * 8 + o]) + fcb[o];
      }
    }
  } else {
    // =========================== LAYER 1 ===========================
    for (int t = 0; t < kT; ++t) {
      if (kw == 0 && alive)  // h0(t) ready; h1(t-1) ready (data + WAR)
        alive = pollb(b0l, (unsigned)(t + 2), b1l, (unsigned)(t + 1));
      __syncthreads();

      f32x16 acc00 = zero16(), acc01 = zero16(), acc10 = zero16(), acc11 = zero16();
      const char* hbA = region(t & 1, 0, bc);   // h0(t), ksteps 0..31
      const char* hbB = region(t & 1, 1, bc);   // h1(t-1), ksteps 32..63
      unsigned long long abuf[2][16];
#pragma unroll
      for (int i = 0; i < 4; ++i) {  // prefetch group 0
        const char* base = hbA;
        const size_t off = (size_t)((2 * (kw + 4 * i) + hi5) * 64 + l31) * 16;
        const unsigned long long* p = (const unsigned long long*)(base + off);
        abuf[0][i * 4 + 0] = ald64(p);
        abuf[0][i * 4 + 1] = ald64(p + 1);
        const unsigned long long* q2 = (const unsigned long long*)(base + off + 512);
        abuf[0][i * 4 + 2] = ald64(q2);
        abuf[0][i * 4 + 3] = ald64(q2 + 1);
      }
#pragma unroll
      for (int g = 0; g < 4; ++g) {
        if (g < 3) {
          const int gn = g + 1;
#pragma unroll
          for (int i = 0; i < 4; ++i) {
            const int m = gn * 4 + i;
            const char* base = (m < 8) ? hbA : hbB;
            const int jl = (kw + 4 * m) & 31;
            const size_t off = (size_t)((2 * jl + hi5) * 64 + l31) * 16;
            const unsigned long long* p = (const unsigned long long*)(base + off);
            abuf[gn & 1][i * 4 + 0] = ald64(p);
            abuf[gn & 1][i * 4 + 1] = ald64(p + 1);
            const unsigned long long* q2 = (const unsigned long long*)(base + off + 512);
            abuf[gn & 1][i * 4 + 2] = ald64(q2);
            abuf[gn & 1][i * 4 + 3] = ald64(q2 + 1);
          }
        }
#pragma unroll
        for (int i = 0; i < 4; ++i) {
          const int m = g * 4 + i;
          union { unsigned long long u[2]; bf16x8 v; } a0, a1;
          a0.u[0] = abuf[g & 1][i * 4 + 0]; a0.u[1] = abuf[g & 1][i * 4 + 1];
          a1.u[0] = abuf[g & 1][i * 4 + 2]; a1.u[1] = abuf[g & 1][i * 4 + 3];
          acc00 = MFMA32(a0.v, wf[0][m], acc00);
          acc01 = MFMA32(a0.v, wf[1][m], acc01);
          acc10 = MFMA32(a1.v, wf[0][m], acc10);
          acc11 = MFMA32(a1.v, wf[1][m], acc11);
        }
      }
      PARTS_WRITE(acc00, 0, 0); PARTS_WRITE(acc01, 0, 1);
      PARTS_WRITE(acc10, 1, 0); PARTS_WRITE(acc11, 1, 1);
      __syncthreads();
      cell_update();
      __syncthreads();
      h_publish(region((t & 1) ^ 1, 1, bc));
      if (t >= kSeq - 1) {  // y(t) partials -> yacc[t&1]
        const int q = t & 1;
#pragma unroll
        for (int rep2 = 0; rep2 < 2; ++rep2) {
          const int i2 = tid + rep2 * 256;
          const int r = i2 >> 3, o = i2 & 7;
          float s = 0.0f;
#pragma unroll
          for (int h2 = 0; h2 < 16; ++h2)
            s += bf2f(hloc[r * 24 + h2]) * fcwl[o][h2];
          atomicAdd(&yacc[(size_t)(q * 512 + b0 + r) * 8 + o], s);
        }
      }
      relwait();
      __syncthreads();
      if (tid == 0) signal(cnt1, 1);
    }
  }
}

extern "C" void kernel_launch(void* const* d_in, const int* in_sizes, int n_in,
                              void* d_out, int out_size, void* d_ws, size_t ws_size,
                              hipStream_t stream) {
  (void)in_sizes; (void)n_in; (void)out_size; (void)ws_size;
  hipMemsetAsync((char*)d_ws + kWsZeroBegin, 0, kWsZeroSize, stream);

  const float* x    = (const float*)d_in[0];
  const float* ft   = (const float*)d_in[1];
  const float* h0in = (const float*)d_in[2];
  const float* c0in = (const float*)d_in[3];
  const float* wih0 = (const float*)d_in[4];
  const float* whh0 = (const float*)d_in[5];
  const float* bih0 = (const float*)d_in[6];
  const float* bhh0 = (const float*)d_in[7];
  const float* wih1 = (const float*)d_in[8];
  const float* whh1 = (const float*)d_in[9];
  const float* bih1 = (const float*)d_in[10];
  const float* bhh1 = (const float*)d_in[11];
  const float* fcw  = (const float*)d_in[12];
  const float* fcb  = (const float*)d_in[13];
  float* out = (float*)d_out;
  char* ws = (char*)d_ws;

  void* args[] = {&x, &ft, &h0in, &c0in, &wih0, &whh0, &bih0, &bhh0,
                  &wih1, &whh1, &bih1, &bhh1, &fcw, &fcb, &out, &ws};
  hipError_t err = hipLaunchCooperativeKernel((void*)lstm_persist, dim3(512),
                                              dim3(256), args, 0, stream);
  if (err != hipSuccess) {
    lstm_persist<<<dim3(512), dim3(256), 0, stream>>>(
        x, ft, h0in, c0in, wih0, whh0, bih0, bhh0,
        wih1, whh1, bih1, bhh1, fcw, fcb, out, ws);
  }
}